// Round 4
// baseline (122.152 us; speedup 1.0000x reference)
//
#include <hip/hip_runtime.h>
#include <math.h>

typedef __attribute__((ext_vector_type(8))) short short8;
typedef __attribute__((ext_vector_type(4))) float floatx4;

__device__ __forceinline__ unsigned short f2bf(float f) {
    unsigned int u = __builtin_bit_cast(unsigned int, f);
    u += 0x7FFFu + ((u >> 16) & 1u);   // round-to-nearest-even
    return (unsigned short)(u >> 16);
}

// ---------------------------------------------------------------------------
// ws layout (bytes):
//   Wallb bf16 [1536][512] @ 0        (Wq rows 0-511, Wk 512-1023, Wv 1024-1535)
//   xb    bf16 [512][512]  @ 1572864  ([t][d])
//   Wob   bf16 [512][512]  @ 2097152  ([o][d])
//   attTb bf16 [512][512]  @ 2621440  ([t][d]) -- written scattered by attn
//   qkvf  f32  [1536][512] @ 3145728  ([o'][t]; q 0-511, k 512-1023, v 1024-1535)
// ---------------------------------------------------------------------------

// ---------------------------------------------------------------------------
// Kernel 1: fp32 -> bf16 for x, Wq, Wk, Wv, Wo.
// ---------------------------------------------------------------------------
__global__ __launch_bounds__(256) void cvt_bf16(
    const float* __restrict__ x,  const float* __restrict__ Wq,
    const float* __restrict__ Wk, const float* __restrict__ Wv,
    const float* __restrict__ Wo, unsigned short* __restrict__ Wallb,
    unsigned short* __restrict__ xb, unsigned short* __restrict__ Wob)
{
    const float* src; unsigned short* dst;
    switch (blockIdx.y) {
        case 0: src = Wq; dst = Wallb;          break;
        case 1: src = Wk; dst = Wallb + 262144; break;
        case 2: src = Wv; dst = Wallb + 524288; break;
        case 3: src = x;  dst = xb;             break;
        default: src = Wo; dst = Wob;           break;
    }
    const int i4 = (blockIdx.x * 256 + threadIdx.x) * 4;
    const float4 v = *(const float4*)(src + i4);
    ushort4 o;
    o.x = f2bf(v.x); o.y = f2bf(v.y); o.z = f2bf(v.z); o.w = f2bf(v.w);
    *(ushort4*)(dst + i4) = o;
}

// ---------------------------------------------------------------------------
// Kernel 2/4: LDS-free wave-tile MFMA GEMM. C[m][n] = sum_k A[m][k]*B[n][k].
// One 64-thread block = one wave = one independent 32x32 C-tile.
// Fragments loaded straight from global (L2-resident), no barriers at all.
// K=512, ld=512 fixed. Grid: (M/32)*16 blocks; mtile = bx>>4, ntile = bx&15.
// A-frag (m89-verified layout): lane holds A[m= l&15][k = (l>>4)*8 + 0..7].
// ---------------------------------------------------------------------------
__global__ __launch_bounds__(64) void gemm_wave(
    const unsigned short* __restrict__ A, const unsigned short* __restrict__ B,
    float* __restrict__ C)
{
    const int lane = threadIdx.x;
    const int quad = lane >> 4, l15 = lane & 15;
    const int m0 = (blockIdx.x >> 4) * 32;
    const int n0 = (blockIdx.x & 15) * 32;

    floatx4 acc[2][2] = {{{0.f,0.f,0.f,0.f},{0.f,0.f,0.f,0.f}},
                         {{0.f,0.f,0.f,0.f},{0.f,0.f,0.f,0.f}}};

    const unsigned short* a0 = A + (m0 + l15) * 512 + quad * 8;
    const unsigned short* a1 = a0 + 16 * 512;
    const unsigned short* b0 = B + (n0 + l15) * 512 + quad * 8;
    const unsigned short* b1 = b0 + 16 * 512;

    #pragma unroll 4
    for (int kc = 0; kc < 512; kc += 32) {
        const short8 av0 = *(const short8*)(a0 + kc);
        const short8 av1 = *(const short8*)(a1 + kc);
        const short8 bv0 = *(const short8*)(b0 + kc);
        const short8 bv1 = *(const short8*)(b1 + kc);
        acc[0][0] = __builtin_amdgcn_mfma_f32_16x16x32_bf16(av0, bv0, acc[0][0], 0, 0, 0);
        acc[0][1] = __builtin_amdgcn_mfma_f32_16x16x32_bf16(av0, bv1, acc[0][1], 0, 0, 0);
        acc[1][0] = __builtin_amdgcn_mfma_f32_16x16x32_bf16(av1, bv0, acc[1][0], 0, 0, 0);
        acc[1][1] = __builtin_amdgcn_mfma_f32_16x16x32_bf16(av1, bv1, acc[1][1], 0, 0, 0);
    }

    // C/D layout: row = quad*4 + r, col = lane&15 (m89-verified)
    #pragma unroll
    for (int mt = 0; mt < 2; ++mt)
        #pragma unroll
        for (int nt = 0; nt < 2; ++nt) {
            const int grow = m0 + mt * 16 + quad * 4;
            const int gcol = n0 + nt * 16 + l15;
            #pragma unroll
            for (int r = 0; r < 4; ++r)
                C[(grow + r) * 512 + gcol] = acc[mt][nt][r];
        }
}

// ---------------------------------------------------------------------------
// Kernel 3: fused RoPE + per-channel scalar causal attention, 4 i's/thread.
// Block = one channel (512 blocks), 128 threads, thread owns i = 128r + tid.
// Wave w: j-block B is unmasked for r when B < 2r+w, masked when B == 2r+w
// (mask reduces to jj+u <= lane), skipped when B > 2r+w. Each broadcast k/v
// LDS read feeds 16 j-units -> LDS-pipe cost /4 vs 1 i/thread.
// Output written directly as bf16 into attTb[t][d] (scattered column).
// ---------------------------------------------------------------------------
__global__ __launch_bounds__(128) void attn_rope4(
    const float* __restrict__ qkv, unsigned short* __restrict__ attTb)
{
    const int ch   = blockIdx.x;
    const int tid  = threadIdx.x;
    const int w    = tid >> 6;
    const int lane = tid & 63;
    const int p    = ch ^ 256;
    const float sgn = (ch < 256) ? -1.f : 1.f;

    __shared__ float ks_[512];
    __shared__ float vs_[512];
    __shared__ float cs_[512];
    __shared__ float sn_[512];

    const float* __restrict__ qg = qkv;
    const float* __restrict__ kg = qkv + 262144;
    const float* __restrict__ vg = qkv + 524288;

    const float inv_freq = powf(10000.f, -(float)(ch & 31) * (1.f / 32.f));

    // Stage + RoPE k (scale 1/8 folded in), stage v, build sincos table.
    {
        const int t0 = tid * 4;
        const float4 kc4 = *(const float4*)(kg + ch * 512 + t0);
        const float4 kp4 = *(const float4*)(kg + p  * 512 + t0);
        const float4 vv4 = *(const float4*)(vg + ch * 512 + t0);
        const float kc_[4] = {kc4.x, kc4.y, kc4.z, kc4.w};
        const float kp_[4] = {kp4.x, kp4.y, kp4.z, kp4.w};
        const float vv_[4] = {vv4.x, vv4.y, vv4.z, vv4.w};
        #pragma unroll
        for (int u = 0; u < 4; ++u) {
            float sn, cs;
            sincosf((float)(t0 + u) * inv_freq, &sn, &cs);
            ks_[t0 + u] = (kc_[u] * cs + sgn * kp_[u] * sn) * 0.125f;
            vs_[t0 + u] = vv_[u];
            cs_[t0 + u] = cs;
            sn_[t0 + u] = sn;
        }
    }
    __syncthreads();

    float qi[4], l[4] = {0.f, 0.f, 0.f, 0.f}, acc[4] = {0.f, 0.f, 0.f, 0.f};
    #pragma unroll
    for (int r = 0; r < 4; ++r) {
        const int i = r * 128 + tid;
        qi[r] = qg[ch * 512 + i] * cs_[i] + sgn * qg[p * 512 + i] * sn_[i];
    }

    const int Bmax = 6 + w;                    // wave-uniform
    for (int B = 0; B <= Bmax; ++B) {
        const int bm = B - w;                  // vs 2r: < unmasked, == masked
        for (int jj = 0; jj < 64; jj += 4) {
            const float4 k4 = *(const float4*)&ks_[B * 64 + jj];
            const float4 v4 = *(const float4*)&vs_[B * 64 + jj];
            #pragma unroll
            for (int r = 0; r < 4; ++r) {
                if (bm > 2 * r) continue;      // uniform: this r is done
                if (bm < 2 * r) {              // fully unmasked
                    float e;
                    e = __expf(qi[r] * k4.x); l[r] += e; acc[r] = fmaf(e, v4.x, acc[r]);
                    e = __expf(qi[r] * k4.y); l[r] += e; acc[r] = fmaf(e, v4.y, acc[r]);
                    e = __expf(qi[r] * k4.z); l[r] += e; acc[r] = fmaf(e, v4.z, acc[r]);
                    e = __expf(qi[r] * k4.w); l[r] += e; acc[r] = fmaf(e, v4.w, acc[r]);
                } else {                       // boundary block: mask jj+u <= lane
                    float e;
                    e = (jj + 0 <= lane) ? __expf(qi[r] * k4.x) : 0.f; l[r] += e; acc[r] = fmaf(e, v4.x, acc[r]);
                    e = (jj + 1 <= lane) ? __expf(qi[r] * k4.y) : 0.f; l[r] += e; acc[r] = fmaf(e, v4.y, acc[r]);
                    e = (jj + 2 <= lane) ? __expf(qi[r] * k4.z) : 0.f; l[r] += e; acc[r] = fmaf(e, v4.z, acc[r]);
                    e = (jj + 3 <= lane) ? __expf(qi[r] * k4.w) : 0.f; l[r] += e; acc[r] = fmaf(e, v4.w, acc[r]);
                }
            }
        }
    }

    #pragma unroll
    for (int r = 0; r < 4; ++r)
        attTb[(r * 128 + tid) * 512 + ch] = f2bf(acc[r] / l[r]);
}

// ---------------------------------------------------------------------------
extern "C" void kernel_launch(void* const* d_in, const int* in_sizes, int n_in,
                              void* d_out, int out_size, void* d_ws, size_t ws_size,
                              hipStream_t stream)
{
    const float* x  = (const float*)d_in[0];
    const float* Wq = (const float*)d_in[1];
    const float* Wk = (const float*)d_in[2];
    const float* Wv = (const float*)d_in[3];
    const float* Wo = (const float*)d_in[4];
    float* out = (float*)d_out;

    unsigned short* Wallb = (unsigned short*)d_ws;        // 786432 bf16
    unsigned short* xb    = Wallb + 786432;               // 262144
    unsigned short* Wob   = xb + 262144;                  // 262144
    unsigned short* attTb = Wob + 262144;                 // 262144
    float* qkvf = (float*)(attTb + 262144);               // 786432 f32

    cvt_bf16<<<dim3(256, 5), 256, 0, stream>>>(x, Wq, Wk, Wv, Wo, Wallb, xb, Wob);
    // qkv: C[o'][t] = sum_d Wall[o'][d] * x[t][d]   (M=1536 -> 48*16=768 blocks)
    gemm_wave<<<768, 64, 0, stream>>>(Wallb, xb, qkvf);
    attn_rope4<<<512, 128, 0, stream>>>(qkvf, attTb);
    // out: C[t][o] = sum_d attT[t][d] * Wo[o][d]    (M=512 -> 16*16=256 blocks)
    gemm_wave<<<256, 64, 0, stream>>>(attTb, Wob, out);
}

// Round 5
// 106.373 us; speedup vs baseline: 1.1483x; 1.1483x over previous
//
#include <hip/hip_runtime.h>
#include <math.h>

typedef __attribute__((ext_vector_type(8))) short short8;
typedef __attribute__((ext_vector_type(4))) float floatx4;

__device__ __forceinline__ unsigned short f2bf(float f) {
    unsigned int u = __builtin_bit_cast(unsigned int, f);
    u += 0x7FFFu + ((u >> 16) & 1u);   // round-to-nearest-even
    return (unsigned short)(u >> 16);
}

// ---------------------------------------------------------------------------
// ws layout:
//   Wallb bf16 [1536][512] (Wq 0-511, Wk 512-1023, Wv 1024-1535)
//   xb    bf16 [512][512]  ([t][d])
//   Wob   bf16 [512][512]  ([o][d])
//   attTb bf16 [512][512]  ([t][d])  (scattered column writes from attn)
//   qkvf  f32  [1536][512] ([o'][t])
// ---------------------------------------------------------------------------

__global__ __launch_bounds__(256) void cvt_bf16(
    const float* __restrict__ x,  const float* __restrict__ Wq,
    const float* __restrict__ Wk, const float* __restrict__ Wv,
    const float* __restrict__ Wo, unsigned short* __restrict__ Wallb,
    unsigned short* __restrict__ xb, unsigned short* __restrict__ Wob)
{
    const float* src; unsigned short* dst;
    switch (blockIdx.y) {
        case 0: src = Wq; dst = Wallb;          break;
        case 1: src = Wk; dst = Wallb + 262144; break;
        case 2: src = Wv; dst = Wallb + 524288; break;
        case 3: src = x;  dst = xb;             break;
        default: src = Wo; dst = Wob;           break;
    }
    const int i4 = (blockIdx.x * 256 + threadIdx.x) * 4;
    const float4 v = *(const float4*)(src + i4);
    ushort4 o;
    o.x = f2bf(v.x); o.y = f2bf(v.y); o.z = f2bf(v.z); o.w = f2bf(v.w);
    *(ushort4*)(dst + i4) = o;
}

// ---------------------------------------------------------------------------
// LDS-free wave-tile MFMA GEMM with depth-2 register pipeline.
// One 64-thread block = one 32x32 C-tile. C[m][n] = sum_k A[m][k]*B[n][k].
// K=512, ld=512. Grid (M/32)*16; mtile = bx>>4, ntile = bx&15. No barriers.
// ---------------------------------------------------------------------------
__global__ __launch_bounds__(64) void gemm_wave(
    const unsigned short* __restrict__ A, const unsigned short* __restrict__ B,
    float* __restrict__ C)
{
    const int lane = threadIdx.x;
    const int quad = lane >> 4, l15 = lane & 15;
    const int m0 = (blockIdx.x >> 4) * 32;
    const int n0 = (blockIdx.x & 15) * 32;

    const unsigned short* a0 = A + (m0 + l15) * 512 + quad * 8;
    const unsigned short* a1 = a0 + 16 * 512;
    const unsigned short* b0 = B + (n0 + l15) * 512 + quad * 8;
    const unsigned short* b1 = b0 + 16 * 512;

    floatx4 acc[2][2] = {{{0.f,0.f,0.f,0.f},{0.f,0.f,0.f,0.f}},
                         {{0.f,0.f,0.f,0.f},{0.f,0.f,0.f,0.f}}};

    // depth-2 pipeline: cur (kc), nxt (kc+32); prefetch kc+64 during MFMAs
    short8 a0c = *(const short8*)(a0);      short8 a1c = *(const short8*)(a1);
    short8 b0c = *(const short8*)(b0);      short8 b1c = *(const short8*)(b1);
    short8 a0n = *(const short8*)(a0 + 32); short8 a1n = *(const short8*)(a1 + 32);
    short8 b0n = *(const short8*)(b0 + 32); short8 b1n = *(const short8*)(b1 + 32);

    #pragma unroll
    for (int kc = 0; kc < 512; kc += 32) {
        short8 a0f, a1f, b0f, b1f;
        if (kc + 64 < 512) {
            a0f = *(const short8*)(a0 + kc + 64); a1f = *(const short8*)(a1 + kc + 64);
            b0f = *(const short8*)(b0 + kc + 64); b1f = *(const short8*)(b1 + kc + 64);
        }
        acc[0][0] = __builtin_amdgcn_mfma_f32_16x16x32_bf16(a0c, b0c, acc[0][0], 0, 0, 0);
        acc[0][1] = __builtin_amdgcn_mfma_f32_16x16x32_bf16(a0c, b1c, acc[0][1], 0, 0, 0);
        acc[1][0] = __builtin_amdgcn_mfma_f32_16x16x32_bf16(a1c, b0c, acc[1][0], 0, 0, 0);
        acc[1][1] = __builtin_amdgcn_mfma_f32_16x16x32_bf16(a1c, b1c, acc[1][1], 0, 0, 0);
        a0c = a0n; a1c = a1n; b0c = b0n; b1c = b1n;
        a0n = a0f; a1n = a1f; b0n = b0f; b1n = b1f;
    }

    // C/D layout: row = quad*4 + r, col = lane&15 (m89-verified)
    #pragma unroll
    for (int mt = 0; mt < 2; ++mt)
        #pragma unroll
        for (int nt = 0; nt < 2; ++nt) {
            const int grow = m0 + mt * 16 + quad * 4;
            const int gcol = n0 + nt * 16 + l15;
            #pragma unroll
            for (int r = 0; r < 4; ++r)
                C[(grow + r) * 512 + gcol] = acc[mt][nt][r];
        }
}

// ---------------------------------------------------------------------------
// Fused RoPE + per-channel scalar causal attention. IPT=2.
// Block = one channel (512 blocks), 256 threads; thread owns i0=tid, i1=tid+256.
// Wave w phases (all bounds wave-uniform, bodies branch-free):
//   P1: j in [0,64w)            unmasked for i0 & i1
//   P2: j in [64w,64w+64)       boundary i0 (jj+u<=lane), unmasked i1
//   P3: j in [64w+64,256+64w)   unmasked i1 only
//   P4: j in [256+64w,+64)      boundary i1 (jj+u<=lane)
// No max-subtraction (|q*k/8| < ~4: exp safe; same math as ref).
// Output written as bf16 into attTb[t][d] (t=i, d=ch).
// ---------------------------------------------------------------------------
__global__ __launch_bounds__(256) void attn_rope2(
    const float* __restrict__ qkv, unsigned short* __restrict__ attTb)
{
    const int ch   = blockIdx.x;
    const int tid  = threadIdx.x;
    const int w    = tid >> 6;
    const int lane = tid & 63;
    const int p    = ch ^ 256;
    const float sgn = (ch < 256) ? -1.f : 1.f;

    __shared__ float ks_[512];
    __shared__ float vs_[512];
    __shared__ float cs_[512];
    __shared__ float sn_[512];

    const float* __restrict__ qg = qkv;
    const float* __restrict__ kg = qkv + 262144;
    const float* __restrict__ vg = qkv + 524288;

    const float inv_freq = powf(10000.f, -(float)(ch & 31) * (1.f / 32.f));

    // Stage + RoPE k (1/8 folded), stage v, sincos tables. Stride-1 writes.
    #pragma unroll
    for (int h = 0; h < 2; ++h) {
        const int t = tid + h * 256;
        float sn, cs;
        sincosf((float)t * inv_freq, &sn, &cs);
        ks_[t] = (kg[ch * 512 + t] * cs + sgn * kg[p * 512 + t] * sn) * 0.125f;
        vs_[t] = vg[ch * 512 + t];
        cs_[t] = cs;
        sn_[t] = sn;
    }
    __syncthreads();

    const int i0 = tid, i1 = tid + 256;
    const float q0 = qg[ch * 512 + i0] * cs_[i0] + sgn * qg[p * 512 + i0] * sn_[i0];
    const float q1 = qg[ch * 512 + i1] * cs_[i1] + sgn * qg[p * 512 + i1] * sn_[i1];

    float l0 = 0.f, a0 = 0.f, l1 = 0.f, a1 = 0.f;
    const int jw = w * 64;   // wave-uniform

    // P1: both unmasked
    for (int j = 0; j < jw; j += 4) {
        const float4 k4 = *(const float4*)&ks_[j];
        const float4 v4 = *(const float4*)&vs_[j];
        float e;
        e = __expf(q0 * k4.x); l0 += e; a0 = fmaf(e, v4.x, a0);
        e = __expf(q1 * k4.x); l1 += e; a1 = fmaf(e, v4.x, a1);
        e = __expf(q0 * k4.y); l0 += e; a0 = fmaf(e, v4.y, a0);
        e = __expf(q1 * k4.y); l1 += e; a1 = fmaf(e, v4.y, a1);
        e = __expf(q0 * k4.z); l0 += e; a0 = fmaf(e, v4.z, a0);
        e = __expf(q1 * k4.z); l1 += e; a1 = fmaf(e, v4.z, a1);
        e = __expf(q0 * k4.w); l0 += e; a0 = fmaf(e, v4.w, a0);
        e = __expf(q1 * k4.w); l1 += e; a1 = fmaf(e, v4.w, a1);
    }
    // P2: boundary for i0, unmasked i1
    #pragma unroll
    for (int jj = 0; jj < 64; jj += 4) {
        const float4 k4 = *(const float4*)&ks_[jw + jj];
        const float4 v4 = *(const float4*)&vs_[jw + jj];
        float e;
        e = (jj + 0 <= lane) ? __expf(q0 * k4.x) : 0.f; l0 += e; a0 = fmaf(e, v4.x, a0);
        e = (jj + 1 <= lane) ? __expf(q0 * k4.y) : 0.f; l0 += e; a0 = fmaf(e, v4.y, a0);
        e = (jj + 2 <= lane) ? __expf(q0 * k4.z) : 0.f; l0 += e; a0 = fmaf(e, v4.z, a0);
        e = (jj + 3 <= lane) ? __expf(q0 * k4.w) : 0.f; l0 += e; a0 = fmaf(e, v4.w, a0);
        e = __expf(q1 * k4.x); l1 += e; a1 = fmaf(e, v4.x, a1);
        e = __expf(q1 * k4.y); l1 += e; a1 = fmaf(e, v4.y, a1);
        e = __expf(q1 * k4.z); l1 += e; a1 = fmaf(e, v4.z, a1);
        e = __expf(q1 * k4.w); l1 += e; a1 = fmaf(e, v4.w, a1);
    }
    // P3: i1 only, unmasked (3 blocks of 64)
    for (int j = jw + 64; j < 256 + jw; j += 4) {
        const float4 k4 = *(const float4*)&ks_[j];
        const float4 v4 = *(const float4*)&vs_[j];
        float e;
        e = __expf(q1 * k4.x); l1 += e; a1 = fmaf(e, v4.x, a1);
        e = __expf(q1 * k4.y); l1 += e; a1 = fmaf(e, v4.y, a1);
        e = __expf(q1 * k4.z); l1 += e; a1 = fmaf(e, v4.z, a1);
        e = __expf(q1 * k4.w); l1 += e; a1 = fmaf(e, v4.w, a1);
    }
    // P4: boundary for i1
    #pragma unroll
    for (int jj = 0; jj < 64; jj += 4) {
        const float4 k4 = *(const float4*)&ks_[256 + jw + jj];
        const float4 v4 = *(const float4*)&vs_[256 + jw + jj];
        float e;
        e = (jj + 0 <= lane) ? __expf(q1 * k4.x) : 0.f; l1 += e; a1 = fmaf(e, v4.x, a1);
        e = (jj + 1 <= lane) ? __expf(q1 * k4.y) : 0.f; l1 += e; a1 = fmaf(e, v4.y, a1);
        e = (jj + 2 <= lane) ? __expf(q1 * k4.z) : 0.f; l1 += e; a1 = fmaf(e, v4.z, a1);
        e = (jj + 3 <= lane) ? __expf(q1 * k4.w) : 0.f; l1 += e; a1 = fmaf(e, v4.w, a1);
    }

    attTb[i0 * 512 + ch] = f2bf(a0 / l0);
    attTb[i1 * 512 + ch] = f2bf(a1 / l1);
}

// ---------------------------------------------------------------------------
extern "C" void kernel_launch(void* const* d_in, const int* in_sizes, int n_in,
                              void* d_out, int out_size, void* d_ws, size_t ws_size,
                              hipStream_t stream)
{
    const float* x  = (const float*)d_in[0];
    const float* Wq = (const float*)d_in[1];
    const float* Wk = (const float*)d_in[2];
    const float* Wv = (const float*)d_in[3];
    const float* Wo = (const float*)d_in[4];
    float* out = (float*)d_out;

    unsigned short* Wallb = (unsigned short*)d_ws;        // 786432 bf16
    unsigned short* xb    = Wallb + 786432;               // 262144
    unsigned short* Wob   = xb + 262144;                  // 262144
    unsigned short* attTb = Wob + 262144;                 // 262144
    float* qkvf = (float*)(attTb + 262144);               // 786432 f32

    cvt_bf16<<<dim3(256, 5), 256, 0, stream>>>(x, Wq, Wk, Wv, Wo, Wallb, xb, Wob);
    // qkv: C[o'][t] = sum_d Wall[o'][d] * x[t][d]   (M=1536 -> 48*16=768 blocks)
    gemm_wave<<<768, 64, 0, stream>>>(Wallb, xb, qkvf);
    attn_rope2<<<512, 256, 0, stream>>>(qkvf, attTb);
    // out: C[t][o] = sum_d attT[t][d] * Wo[o][d]    (M=512 -> 16*16=256 blocks)
    gemm_wave<<<256, 64, 0, stream>>>(attTb, Wob, out);
}